// Round 2
// baseline (781.803 us; speedup 1.0000x reference)
//
#include <hip/hip_runtime.h>
#include <stdint.h>

// Problem constants
#define BN_TOTAL 65536      // B*N = 16*4096 rows
#define DDIM 256            // D
#define KCLUST 4096         // K
#define DECAY 0.99f
#define OMD 0.01f           // 1 - DECAY
#define EPSC 1e-5f

// Output layout (float offsets into d_out), reference tuple order:
// z_q_st[16,4096,256], indices[16,4096], loss[], new_embed[4096,256],
// new_cluster_size[4096], new_embed_avg[4096,256]
#define OFF_ZQ   0
#define OFF_IDX  16777216
#define OFF_LOSS 16842752
#define OFF_NE   16842753
#define OFF_NCS  17891329
#define OFF_NEA  17895425

// ws layout (byte offsets):
//  [0,8)        loss accumulator (double, zeroed)
//  [8,12)       tot (float, written by finalize_cs)
//  [4096, +16384)    enorm[4096] f32
//  [20480, +262144)  bidx[65536] int
//  [282624, +2097152)  eh[4096*256] fp16
//  [2379776, +2097152) el[4096*256] fp16 (scaled x4096)
#define WSB_ENORM 4096
#define WSB_BIDX  20480
#define WSB_EH    282624
#define WSB_EL    2379776

typedef _Float16 half8 __attribute__((ext_vector_type(8)));
typedef _Float16 half4 __attribute__((ext_vector_type(4)));
typedef float f32x4 __attribute__((ext_vector_type(4)));

#define MFMA16x32(a, b, c) __builtin_amdgcn_mfma_f32_16x16x32_f16(a, b, c, 0, 0, 0)

// async global->LDS, 16B per lane; LDS dest is wave-uniform-base + lane*16
// (we pass per-lane linear dest; swizzle is applied on the GLOBAL src side)
__device__ __forceinline__ void gload16(const void* gsrc, void* ldst) {
  __builtin_amdgcn_global_load_lds(
      (const __attribute__((address_space(1))) uint32_t*)(uintptr_t)gsrc,
      (__attribute__((address_space(3))) uint32_t*)(uint32_t)(uintptr_t)ldst,
      16, 0, 0);
}

// ---------------- K0: split embed -> fp16 hi/lo (+ row norms) ----------------
// e = eh + el/4096 with |residual| <= |e|*2^-23  (lo pre-scaled so it stays
// in fp16 normal range regardless of MFMA denormal behavior)
__global__ __launch_bounds__(256) void presplit_embed(
    const float* __restrict__ embed, _Float16* __restrict__ eh,
    _Float16* __restrict__ el, float* __restrict__ enorm) {
  const int w = threadIdx.x >> 6;
  const int l = threadIdx.x & 63;
  const int row = blockIdx.x * 4 + w;
  const f32x4 v = *reinterpret_cast<const f32x4*>(embed + (size_t)row * DDIM + l * 4);
  half4 h, lo;
  float s = 0.0f;
  #pragma unroll
  for (int j = 0; j < 4; ++j) {
    const float x = v[j];
    s += x * x;
    const _Float16 hh = (_Float16)x;
    h[j] = hh;
    lo[j] = (_Float16)((x - (float)hh) * 4096.0f);
  }
  *reinterpret_cast<half4*>(eh + (size_t)row * DDIM + l * 4) = h;
  *reinterpret_cast<half4*>(el + (size_t)row * DDIM + l * 4) = lo;
  #pragma unroll
  for (int off = 32; off; off >>= 1) s += __shfl_xor(s, off, 64);
  if (l == 0) enorm[row] = s;
}

// ---------------- K1: MFMA distance + argmin ----------------
// score(m,n) = ||e_n||^2 - 2*dot(z_m,e_n); dot via 3-pass fp16-split MFMA.
// Block: 4 waves x 32 m-rows = 128 rows; sweeps ALL 4096 clusters in 16-col
// tiles -> per-row argmin fully block-local (no atomics).
// LDS: double-buffered e-tile [16 rows x 256 k] hi+lo = 16KB/buf, staged by
// global_load_lds(16B) with XOR-swizzled global src (byte c stored at
// c ^ ((row&7)<<4) within each 512B row) so ds_read_b128 is ~conflict-free.
__global__ __launch_bounds__(256, 2) void dist_argmin(
    const float* __restrict__ z, const _Float16* __restrict__ eh,
    const _Float16* __restrict__ el, const float* __restrict__ enorm,
    int* __restrict__ bidx, float* __restrict__ idx_out) {
  __shared__ _Float16 lbuf[2][8192];  // [buf][hi 4096 | lo 4096] halfs
  const int t = threadIdx.x;
  const int w = t >> 6;
  const int l = t & 63;
  const int lg = l >> 4;   // 0..3
  const int lr = l & 15;   // A-row / B-col / D-col
  const int m0 = blockIdx.x * 128 + w * 32;

  // ---- load z A-fragments, split f32 -> fp16 hi + scaled lo ----
  // A-frag (16x16x32): row = lane&15, k = (lane>>4)*8 + j  (same map as B)
  half8 ah[2][8], al[2][8];
  #pragma unroll
  for (int rg = 0; rg < 2; ++rg) {
    #pragma unroll
    for (int kf = 0; kf < 8; ++kf) {
      const float* zp = z + (size_t)(m0 + rg * 16 + lr) * DDIM + kf * 32 + lg * 8;
      const f32x4 z0 = *reinterpret_cast<const f32x4*>(zp);
      const f32x4 z1 = *reinterpret_cast<const f32x4*>(zp + 4);
      #pragma unroll
      for (int j = 0; j < 4; ++j) {
        const _Float16 h0 = (_Float16)z0[j];
        ah[rg][kf][j] = h0;
        al[rg][kf][j] = (_Float16)((z0[j] - (float)h0) * 4096.0f);
        const _Float16 h1 = (_Float16)z1[j];
        ah[rg][kf][j + 4] = h1;
        al[rg][kf][j + 4] = (_Float16)((z1[j] - (float)h1) * 4096.0f);
      }
    }
  }

  // ---- staging source offsets (swizzle folded into global address) ----
  // dst linear offset q in a tile: row=q>>9, cc=q&511 -> logical byte
  // row*512 + (cc ^ ((row&7)<<4)); global src = base + n0*512 + that.
  int srcoff[2];
  #pragma unroll
  for (int c01 = 0; c01 < 2; ++c01) {
    const int q = c01 * 4096 + t * 16;
    const int row = q >> 9;
    const int cc = q & 511;
    srcoff[c01] = row * 512 + (cc ^ ((row & 7) << 4));
  }
  const char* ehb = (const char*)eh;
  const char* elb = (const char*)el;

#define STAGE(nt, bb)                                                   \
  {                                                                     \
    const int nb_ = (nt) * 8192; /* n0*512 bytes */                     \
    char* d_ = (char*)&lbuf[bb][0];                                     \
    gload16(ehb + nb_ + srcoff[0], d_ + t * 16);                        \
    gload16(ehb + nb_ + srcoff[1], d_ + 4096 + t * 16);                 \
    gload16(elb + nb_ + srcoff[0], d_ + 8192 + t * 16);                 \
    gload16(elb + nb_ + srcoff[1], d_ + 12288 + t * 16);                \
  }

  float minv[2][4];
  int mini[2][4];
  #pragma unroll
  for (int rg = 0; rg < 2; ++rg)
    #pragma unroll
    for (int r = 0; r < 4; ++r) { minv[rg][r] = 3.4e38f; mini[rg][r] = 0; }

  STAGE(0, 0);
  float en_cur = enorm[lr];  // this lane's D-col n = nt*16 + lr

  for (int nt = 0; nt < 256; ++nt) {
    __syncthreads();  // compiler drains vmcnt(0) here -> buf[nt&1] ready
    if (nt + 1 < 256) STAGE(nt + 1, (nt + 1) & 1);
    float en_next = (nt + 1 < 256) ? enorm[(nt + 1) * 16 + lr] : 0.0f;

    const char* bb = (const char*)&lbuf[nt & 1][0];
    f32x4 acc_h[2], acc_xa[2], acc_xb[2];
    #pragma unroll
    for (int rg = 0; rg < 2; ++rg) {
      acc_h[rg] = f32x4{0.f, 0.f, 0.f, 0.f};
      acc_xa[rg] = f32x4{0.f, 0.f, 0.f, 0.f};
      acc_xb[rg] = f32x4{0.f, 0.f, 0.f, 0.f};
    }
    const int swv = (lr & 7) << 4;
    #pragma unroll
    for (int kf = 0; kf < 8; ++kf) {
      const int ro = lr * 512 + ((kf * 64 + lg * 16) ^ swv);
      const half8 bh = *reinterpret_cast<const half8*>(bb + ro);
      const half8 bl = *reinterpret_cast<const half8*>(bb + 8192 + ro);
      acc_h[0] = MFMA16x32(ah[0][kf], bh, acc_h[0]);
      acc_h[1] = MFMA16x32(ah[1][kf], bh, acc_h[1]);
      acc_xa[0] = MFMA16x32(al[0][kf], bh, acc_xa[0]);
      acc_xa[1] = MFMA16x32(al[1][kf], bh, acc_xa[1]);
      acc_xb[0] = MFMA16x32(ah[0][kf], bl, acc_xb[0]);
      acc_xb[1] = MFMA16x32(ah[1][kf], bl, acc_xb[1]);
    }
    const int n = nt * 16 + lr;
    #pragma unroll
    for (int rg = 0; rg < 2; ++rg) {
      #pragma unroll
      for (int r = 0; r < 4; ++r) {
        const float dot = acc_h[rg][r] + (acc_xa[rg][r] + acc_xb[rg][r]) * (1.0f / 4096.0f);
        const float s = fmaf(-2.0f, dot, en_cur);
        if (s < minv[rg][r]) { minv[rg][r] = s; mini[rg][r] = n; }
      }
    }
    en_cur = en_next;
  }
#undef STAGE

  // reduce across the 16 lanes (lr) holding different cols of the same row
  #pragma unroll
  for (int mask = 1; mask < 16; mask <<= 1) {
    #pragma unroll
    for (int rg = 0; rg < 2; ++rg) {
      #pragma unroll
      for (int r = 0; r < 4; ++r) {
        const float ov = __shfl_xor(minv[rg][r], mask, 64);
        const int oi = __shfl_xor(mini[rg][r], mask, 64);
        if (ov < minv[rg][r] || (ov == minv[rg][r] && oi < mini[rg][r])) {
          minv[rg][r] = ov;
          mini[rg][r] = oi;
        }
      }
    }
  }
  if (lr == 0) {
    #pragma unroll
    for (int rg = 0; rg < 2; ++rg) {
      #pragma unroll
      for (int r = 0; r < 4; ++r) {
        const int row = m0 + rg * 16 + lg * 4 + r;  // D row = (l>>4)*4 + r
        bidx[row] = mini[rg][r];
        idx_out[row] = (float)mini[rg][r];
      }
    }
  }
}

// ---------------- K2: gather z_q, loss partial, EMA scatter ----------------
__global__ __launch_bounds__(256) void gather_scatter(
    const float* __restrict__ z, const float* __restrict__ embed,
    const int* __restrict__ bidx, float* __restrict__ out,
    float* __restrict__ es_acc, float* __restrict__ cnt_acc,
    double* __restrict__ loss_acc) {
  const int w = threadIdx.x >> 6;
  const int lane = threadIdx.x & 63;
  const int base = blockIdx.x * 16 + w * 4;
  float lsum = 0.0f;
  #pragma unroll
  for (int rr = 0; rr < 4; ++rr) {
    const int row = base + rr;
    const int k = bidx[row];
    const float4 zv = *reinterpret_cast<const float4*>(z + (size_t)row * DDIM + lane * 4);
    const float4 ev = *reinterpret_cast<const float4*>(embed + (size_t)k * DDIM + lane * 4);
    float4 zq;
    zq.x = zv.x + (ev.x - zv.x);
    zq.y = zv.y + (ev.y - zv.y);
    zq.z = zv.z + (ev.z - zv.z);
    zq.w = zv.w + (ev.w - zv.w);
    *reinterpret_cast<float4*>(out + OFF_ZQ + (size_t)row * DDIM + lane * 4) = zq;
    const float dx = ev.x - zv.x, dy = ev.y - zv.y, dz = ev.z - zv.z, dw = ev.w - zv.w;
    lsum += dx * dx + dy * dy + dz * dz + dw * dw;
    float* es = es_acc + (size_t)k * DDIM + lane * 4;
    atomicAdd(es + 0, zv.x);
    atomicAdd(es + 1, zv.y);
    atomicAdd(es + 2, zv.z);
    atomicAdd(es + 3, zv.w);
    if (lane == 0) atomicAdd(cnt_acc + k, 1.0f);
  }
  #pragma unroll
  for (int off = 32; off; off >>= 1) lsum += __shfl_xor(lsum, off, 64);
  if (lane == 0) atomicAdd(loss_acc, (double)lsum);
}

// ---------------- K3: new_cluster_size, tot, loss ----------------
__global__ __launch_bounds__(1024) void finalize_cs(
    const float* __restrict__ cluster_size, float* __restrict__ out,
    const double* __restrict__ loss_acc, float* __restrict__ tot_out) {
  __shared__ float red[16];
  const int t = threadIdx.x;
  float local = 0.0f;
  #pragma unroll
  for (int i = 0; i < 4; ++i) {
    const int k = t * 4 + i;
    const float cnt = out[OFF_NCS + k];
    const float ncs = cluster_size[k] * DECAY + OMD * cnt;
    out[OFF_NCS + k] = ncs;
    local += ncs;
  }
  #pragma unroll
  for (int off = 32; off; off >>= 1) local += __shfl_xor(local, off, 64);
  if ((t & 63) == 0) red[t >> 6] = local;
  __syncthreads();
  if (t < 16) {
    float v = red[t];
    #pragma unroll
    for (int off = 8; off; off >>= 1) v += __shfl_xor(v, off, 16);
    if (t == 0) {
      tot_out[0] = v;
      out[OFF_LOSS] = (float)(2.0 * loss_acc[0] / 16777216.0);
    }
  }
}

// ---------------- K4: new_embed_avg (in place) + new_embed ----------------
__global__ __launch_bounds__(256) void finalize_embed(
    const float* __restrict__ embed_avg, float* __restrict__ out,
    const float* __restrict__ tot_p) {
  const int e = blockIdx.x * 256 + threadIdx.x;
  const int k = e >> 8;
  const float tot = tot_p[0];
  const float es = out[OFF_NEA + e];
  const float nea = embed_avg[e] * DECAY + OMD * es;
  const float ncs = out[OFF_NCS + k];
  const float csn = (ncs + EPSC) / (tot + (float)KCLUST * EPSC) * tot;
  out[OFF_NEA + e] = nea;
  out[OFF_NE + e] = nea / csn;
}

extern "C" void kernel_launch(void* const* d_in, const int* in_sizes, int n_in,
                              void* d_out, int out_size, void* d_ws, size_t ws_size,
                              hipStream_t stream) {
  const float* z = (const float*)d_in[0];
  const float* embed = (const float*)d_in[1];
  const float* cluster_size = (const float*)d_in[2];
  const float* embed_avg = (const float*)d_in[3];
  float* out = (float*)d_out;
  char* wsb = (char*)d_ws;
  double* loss_acc = (double*)wsb;
  float* tot_p = (float*)(wsb + 8);
  float* enorm = (float*)(wsb + WSB_ENORM);
  int* bidx = (int*)(wsb + WSB_BIDX);
  _Float16* eh = (_Float16*)(wsb + WSB_EH);
  _Float16* el = (_Float16*)(wsb + WSB_EL);

  // zero accumulators (harness poisons everything with 0xAA)
  hipMemsetAsync(wsb, 0, 16, stream);                                  // loss, tot
  hipMemsetAsync(out + OFF_NCS, 0, (size_t)KCLUST * 4, stream);        // counts acc
  hipMemsetAsync(out + OFF_NEA, 0, (size_t)KCLUST * DDIM * 4, stream); // es acc

  presplit_embed<<<KCLUST / 4, 256, 0, stream>>>(embed, eh, el, enorm);
  dist_argmin<<<BN_TOTAL / 128, 256, 0, stream>>>(z, eh, el, enorm, bidx, out + OFF_IDX);
  gather_scatter<<<BN_TOTAL / 16, 256, 0, stream>>>(
      z, embed, bidx, out, out + OFF_NEA, out + OFF_NCS, loss_acc);
  finalize_cs<<<1, 1024, 0, stream>>>(cluster_size, out, loss_acc, tot_p);
  finalize_embed<<<KCLUST, 256, 0, stream>>>(embed_avg, out, tot_p);
}